// Round 5
// baseline (657.082 us; speedup 1.0000x reference)
//
#include <hip/hip_runtime.h>

// Problem constants
#define BATCH   4096
#define NF      39          // num_field
#define ED      16          // embedding size
#define IN_DIM  624         // NF*ED
#define DW      400
#define BN_EPS  1e-5f
#define KTOT    2496        // CIN K = 39 m * 64 h (h padded)
#define NKSG    78          // KTOT/32
#define AK1     640         // padded deep K for layer 1 input (624 -> 640)
#define NKS1    20          // AK1/32
#define NKS2    13          // 400 -> 416 padded

typedef __attribute__((ext_vector_type(8))) short short8;
typedef __attribute__((ext_vector_type(4))) float f32x4;
typedef unsigned short u16;

__device__ inline unsigned pack2_trunc(float a, float b) {
  return (__float_as_uint(a) >> 16) | (__float_as_uint(b) & 0xffff0000u);
}
__device__ inline unsigned bf16_rne(float f) {
  unsigned u = __float_as_uint(f);
  u += 0x7fff + ((u >> 16) & 1);
  return u >> 16;
}
__device__ inline float bf2f(u16 v) { return __uint_as_float((unsigned)v << 16); }

#define CIN_E (NKSG * 128 * 32)
#define D1_E  (NKS1 * 400 * 32)
#define D2_E  (NKS2 * 400 * 32)
#define PREP_E (CIN_E + D1_E + D2_E + 1600)
#define PREP_B ((PREP_E + 255) / 256)

// ---------------------------------------------------------------------------
// Merged kernel: blocks < BATCH do the embedding gather (+linear part);
// blocks >= BATCH do weight pre-pack + BN-stat zeroing. One launch.
// ---------------------------------------------------------------------------
__global__ __launch_bounds__(256) void k_gp(const int* __restrict__ idx,
    const float* __restrict__ emb, const float* __restrict__ lw,
    const float* __restrict__ lb, const float* __restrict__ w1,
    const float* __restrict__ w2, const float* __restrict__ dw1,
    const float* __restrict__ dw2, u16* __restrict__ flatb,
    float* __restrict__ lp, u16* __restrict__ wp1, u16* __restrict__ wp2,
    u16* __restrict__ wpd1, u16* __restrict__ wpd2, float* __restrict__ gstat) {
  int t = threadIdx.x;
  if (blockIdx.x < BATCH) {
    int b = blockIdx.x;
    __shared__ int si[NF];
    __shared__ float r4[4];
    if (t < NF) si[t] = idx[b * NF + t];
    __syncthreads();
    float acc = 0.f;
#pragma unroll
    for (int i = 0; i < 3; i++) {
      int e = t + i * 256;
      if (e < IN_DIM) {
        float v = emb[(size_t)si[e >> 4] * ED + (e & 15)];
        flatb[(size_t)b * AK1 + e] = (u16)bf16_rne(v);
        acc = fmaf(v, lw[e], acc);
      } else if (e < AK1) {
        flatb[(size_t)b * AK1 + e] = 0;
      }
    }
#pragma unroll
    for (int k = 1; k < 64; k <<= 1) acc += __shfl_xor(acc, k);
    if ((t & 63) == 0) r4[t >> 6] = acc;
    __syncthreads();
    if (t == 0) lp[b] = r4[0] + r4[1] + r4[2] + r4[3] + lb[0];
  } else {
    int e = (blockIdx.x - BATCH) * 256 + t;
    if (e < CIN_E) {
      int ksg = e >> 12, r = e & 4095, n = r >> 5, kk = r & 31;
      int k = ksg * 32 + kk, h = k & 63, m = k >> 6;
      float v1 = (h < NF) ? w1[(size_t)n * (NF * NF) + h * NF + m] : 0.f;
      float v2 = w2[(size_t)n * (64 * NF) + h * NF + m];
      wp1[e] = (u16)bf16_rne(v1);
      wp2[e] = (u16)bf16_rne(v2);
    } else if (e < CIN_E + D1_E) {
      int e2 = e - CIN_E;
      int ksg = e2 / 12800, r = e2 - ksg * 12800, col = r >> 5, kk = r & 31;
      int k = ksg * 32 + kk;
      wpd1[e2] = (k < IN_DIM) ? (u16)bf16_rne(dw1[(size_t)k * DW + col]) : 0;
    } else if (e < CIN_E + D1_E + D2_E) {
      int e2 = e - CIN_E - D1_E;
      int ksg = e2 / 12800, r = e2 - ksg * 12800, col = r >> 5, kk = r & 31;
      int k = ksg * 32 + kk;
      wpd2[e2] = (k < DW) ? (u16)bf16_rne(dw2[(size_t)k * DW + col]) : 0;
    } else if (e < PREP_E) {
      gstat[e - CIN_E - D1_E - D2_E] = 0.f;
    }
  }
}

// ---------------------------------------------------------------------------
// CIN via MFMA. N-split x2 (grid.y) AND K-split x2 (wave pairs).
// Block = 4 waves = 2 pairs x 2 K-halves; pair p handles samples b0+4p..+3,
// half 0: m in [0,20), half 1: m in [20,39). Partials of half 1 go through
// LDS (32 KB) and are added by half 0, which runs the epilogue.
// B-frags double-buffered from L2; A built in-register. 4 blocks/CU target.
// ---------------------------------------------------------------------------
template <bool LAY2>
__global__ __launch_bounds__(256, 4) void k_cin_mfma(
    const u16* __restrict__ flatb, const u16* __restrict__ nxtg,
    const u16* __restrict__ wp, const float* __restrict__ bias,
    u16* __restrict__ nxt_out, float* __restrict__ res) {
  __shared__ f32x4 lds4[2 * 16 * 64];    // 32 KB
  int t = threadIdx.x;
  int w = t >> 6, lane = t & 63;
  int pair = w >> 1, half = w & 1;
  int nl = lane & 15, q = lane >> 4;
  int d = nl;
  int b0 = blockIdx.x * 8 + pair * 4;
  int c0 = blockIdx.y * 64;
  int M0 = half ? 20 : 0;
  int M1 = half ? NF : 20;
  int NLOC = (M1 - M0) * 2;

  // s1 registers: nxr[si][ks][w4] = packed bf16 pair, h = ks*32+q*8+2*w4(+1)
  unsigned nxr[4][2][4];
  if (LAY2) {
#pragma unroll
    for (int si = 0; si < 4; si++)
#pragma unroll
      for (int ks = 0; ks < 2; ks++) {
        uint4 v = *(const uint4*)(nxtg +
            (((size_t)(b0 + si) * 16 + d) * 64 + ks * 32 + q * 8));
        nxr[si][ks][0] = v.x; nxr[si][ks][1] = v.y;
        nxr[si][ks][2] = v.z; nxr[si][ks][3] = v.w;
      }
  } else {
#pragma unroll
    for (int si = 0; si < 4; si++)
#pragma unroll
      for (int ks = 0; ks < 2; ks++)
#pragma unroll
        for (int w4 = 0; w4 < 4; w4++) {
          int h0 = ks * 32 + q * 8 + 2 * w4;
          int h1 = h0 + 1;
          unsigned u0 = (h0 < NF) ? flatb[(size_t)(b0 + si) * AK1 + h0 * 16 + d] : 0;
          unsigned u1 = (h1 < NF) ? flatb[(size_t)(b0 + si) * AK1 + h1 * 16 + d] : 0;
          nxr[si][ks][w4] = u0 | (u1 << 16);
        }
  }

  f32x4 acc[4][4];
#pragma unroll
  for (int si = 0; si < 4; si++)
#pragma unroll
    for (int nt = 0; nt < 4; nt++) acc[si][nt] = (f32x4){0.f, 0.f, 0.f, 0.f};

  const u16* wbase = wp + (size_t)(c0 + nl) * 32 + q * 8 + (size_t)M0 * 2 * 4096;
  short8 bfr[2][4];
#pragma unroll
  for (int nt = 0; nt < 4; nt++)
    bfr[0][nt] = *(const short8*)(wbase + nt * 512);   // local ksg = 0

  float xv[4], xvn[4];
#pragma unroll
  for (int si = 0; si < 4; si++)
    xv[si] = bf2f(flatb[(size_t)(b0 + si) * AK1 + M0 * 16 + d]);

  for (int m = M0; m < M1; m++) {
    if (m + 1 < M1) {
#pragma unroll
      for (int si = 0; si < 4; si++)
        xvn[si] = bf2f(flatb[(size_t)(b0 + si) * AK1 + (m + 1) * 16 + d]);
    }
#pragma unroll
    for (int ks = 0; ks < 2; ks++) {
      int local = (m - M0) * 2 + ks;
      int cur = local & 1, nx = cur ^ 1;
      if (local + 1 < NLOC) {
        const u16* wb = wbase + (size_t)(local + 1) * 4096;
#pragma unroll
        for (int nt = 0; nt < 4; nt++)
          bfr[nx][nt] = *(const short8*)(wb + nt * 512);
      }
      int mks = (m & 0) + ks;  // ks index into nxr (h depends only on ks)
      short8 afr[4];
#pragma unroll
      for (int si = 0; si < 4; si++) {
        union { unsigned u[4]; short8 s; } a;
#pragma unroll
        for (int w4 = 0; w4 < 4; w4++) {
          unsigned u = nxr[si][mks][w4];
          float lo = __uint_as_float(u << 16) * xv[si];
          float hi = __uint_as_float(u & 0xffff0000u) * xv[si];
          a.u[w4] = pack2_trunc(lo, hi);
        }
        afr[si] = a.s;
      }
#pragma unroll
      for (int nt = 0; nt < 4; nt++)
#pragma unroll
        for (int si = 0; si < 4; si++)
          acc[si][nt] = __builtin_amdgcn_mfma_f32_16x16x32_bf16(
              afr[si], bfr[cur][nt], acc[si][nt], 0, 0, 0);
    }
#pragma unroll
    for (int si = 0; si < 4; si++) xv[si] = xvn[si];
  }

  // K-split reduction: half 1 dumps partials to LDS, half 0 adds.
  if (half) {
#pragma unroll
    for (int si = 0; si < 4; si++)
#pragma unroll
      for (int nt = 0; nt < 4; nt++)
        lds4[(pair * 16 + si * 4 + nt) * 64 + lane] = acc[si][nt];
  }
  __syncthreads();
  if (half) return;
#pragma unroll
  for (int si = 0; si < 4; si++)
#pragma unroll
    for (int nt = 0; nt < 4; nt++) {
      f32x4 p = lds4[(pair * 16 + si * 4 + nt) * 64 + lane];
      acc[si][nt][0] += p[0]; acc[si][nt][1] += p[1];
      acc[si][nt][2] += p[2]; acc[si][nt][3] += p[3];
    }

  // Epilogue. C layout: col = nl (within n-tile), row d' = q*4 + r.
#pragma unroll
  for (int si = 0; si < 4; si++) {
    int b = b0 + si;
#pragma unroll
    for (int nt = 0; nt < 4; nt++) {
      int o = c0 + nt * 16 + nl;
      float bi = bias[o];
      if (!LAY2 && c0 == 0) {
#pragma unroll
        for (int r = 0; r < 4; r++) {
          float v = fmaxf(acc[si][nt][r] + bi, 0.f);
          nxt_out[((size_t)b * 16 + q * 4 + r) * 64 + o] = (u16)bf16_rne(v);
        }
      } else {
        float s = 0.f;
#pragma unroll
        for (int r = 0; r < 4; r++) s += fmaxf(acc[si][nt][r] + bi, 0.f);
        s += __shfl_xor(s, 16);
        s += __shfl_xor(s, 32);
        if (q == 0) {
          int ri = LAY2 ? (64 + o) : (o - 64);
          res[(size_t)b * 192 + ri] = s;
        }
      }
    }
  }
}

// ---------------------------------------------------------------------------
// Deep-tower GEMM via MFMA, occupancy-first: grid (M/64, 25), wave = 16 rows
// x 16 cols (1 n-tile), A+B double-buffered. BN_A folds the *previous*
// layer's BN finalize in-block (from gsIn/gs2In) and applies BN+ReLU to A.
// Fused BN stats of C -> global atomics (gs/gs2).
// ---------------------------------------------------------------------------
template <bool BN_A, int NKS, int KREAL, int AK>
__global__ __launch_bounds__(256) void k_gemm_mfma(
    const u16* __restrict__ Abf, const float* __restrict__ Af32,
    const u16* __restrict__ wp, const float* __restrict__ bias,
    const float* __restrict__ gsIn, const float* __restrict__ gs2In,
    const float* __restrict__ bng, const float* __restrict__ bnb,
    float* __restrict__ C, float* __restrict__ gs, float* __restrict__ gs2) {
  __shared__ float lsS[NKS * 32], lsH[NKS * 32];
  __shared__ float lred[32];
  int t = threadIdx.x;
  if (BN_A) {
    for (int c = t; c < NKS * 32; c += 256) {
      float sc = 0.f, sh = 0.f;
      if (c < DW) {
        float m = gsIn[c] * (1.f / BATCH);
        float var = gs2In[c] * (1.f / BATCH) - m * m;
        sc = bng[c] * rsqrtf(var + BN_EPS);
        sh = bnb[c] - m * sc;
      }
      lsS[c] = sc; lsH[c] = sh;
    }
  }
  if (t < 32) lred[t] = 0.f;
  __syncthreads();

  int w = t >> 6, lane = t & 63;
  int nl = lane & 15, q = lane >> 4;
  int row = blockIdx.x * 64 + w * 16 + nl;
  int c0 = blockIdx.y * 16;
  f32x4 acc = (f32x4){0.f, 0.f, 0.f, 0.f};

  // raw prefetch buffers
  short8 araw[2]; f32x4 fraw0[2], fraw1[2]; short8 braw[2];
  auto loadA_raw = [&](int ksg, int buf) {
    int kb = ksg * 32 + q * 8;
    if (!BN_A) {
      araw[buf] = *(const short8*)(Abf + (size_t)row * AK + kb);
    } else {
      if (kb + 8 <= KREAL) {
        fraw0[buf] = *(const f32x4*)(Af32 + (size_t)row * KREAL + kb);
        fraw1[buf] = *(const f32x4*)(Af32 + (size_t)row * KREAL + kb + 4);
      } else {
        fraw0[buf] = (f32x4){0.f,0.f,0.f,0.f};
        fraw1[buf] = (f32x4){0.f,0.f,0.f,0.f};
      }
    }
    braw[buf] = *(const short8*)(wp + (size_t)ksg * (400 * 32) +
                                 (size_t)(c0 + nl) * 32 + q * 8);
  };
  auto cookA = [&](int ksg, int buf) -> short8 {
    if (!BN_A) return araw[buf];
    int kb = ksg * 32 + q * 8;
    f32x4 s0 = *(const f32x4*)&lsS[kb], h0 = *(const f32x4*)&lsH[kb];
    f32x4 s1 = *(const f32x4*)&lsS[kb + 4], h1 = *(const f32x4*)&lsH[kb + 4];
    union { unsigned u[4]; short8 s; } a;
    float v0 = fmaxf(fmaf(fraw0[buf][0], s0[0], h0[0]), 0.f);
    float v1 = fmaxf(fmaf(fraw0[buf][1], s0[1], h0[1]), 0.f);
    float v2 = fmaxf(fmaf(fraw0[buf][2], s0[2], h0[2]), 0.f);
    float v3 = fmaxf(fmaf(fraw0[buf][3], s0[3], h0[3]), 0.f);
    float v4 = fmaxf(fmaf(fraw1[buf][0], s1[0], h1[0]), 0.f);
    float v5 = fmaxf(fmaf(fraw1[buf][1], s1[1], h1[1]), 0.f);
    float v6 = fmaxf(fmaf(fraw1[buf][2], s1[2], h1[2]), 0.f);
    float v7 = fmaxf(fmaf(fraw1[buf][3], s1[3], h1[3]), 0.f);
    a.u[0] = bf16_rne(v0) | (bf16_rne(v1) << 16);
    a.u[1] = bf16_rne(v2) | (bf16_rne(v3) << 16);
    a.u[2] = bf16_rne(v4) | (bf16_rne(v5) << 16);
    a.u[3] = bf16_rne(v6) | (bf16_rne(v7) << 16);
    return a.s;
  };

  loadA_raw(0, 0);
#pragma unroll 4
  for (int ksg = 0; ksg < NKS; ksg++) {
    int cur = ksg & 1;
    if (ksg + 1 < NKS) loadA_raw(ksg + 1, cur ^ 1);
    short8 afr = cookA(ksg, cur);
    acc = __builtin_amdgcn_mfma_f32_16x16x32_bf16(afr, braw[cur], acc, 0, 0, 0);
  }

  int rbase = blockIdx.x * 64 + w * 16 + q * 4;
  int col = c0 + nl;
  float bi = bias[col];
  float s = 0.f, s2 = 0.f;
#pragma unroll
  for (int r = 0; r < 4; r++) {
    float v = acc[r] + bi;
    C[(size_t)(rbase + r) * DW + col] = v;
    s += v; s2 = fmaf(v, v, s2);
  }
  s += __shfl_xor(s, 16); s2 += __shfl_xor(s2, 16);
  s += __shfl_xor(s, 32); s2 += __shfl_xor(s2, 32);
  if (q == 0) {
    atomicAdd(&lred[nl], s);
    atomicAdd(&lred[16 + nl], s2);
  }
  __syncthreads();
  if (t < 16)       atomicAdd(&gs[c0 + t], lred[t]);
  else if (t < 32)  atomicAdd(&gs2[c0 + t - 16], lred[t]);
}

// ---------------------------------------------------------------------------
// Final concat + dot, with BN2 finalize folded in-block.
// ---------------------------------------------------------------------------
__global__ __launch_bounds__(256) void k_final(const float* __restrict__ lp,
    const float* __restrict__ res, const float* __restrict__ y2,
    const float* __restrict__ gB, const float* __restrict__ gB2,
    const float* __restrict__ g2, const float* __restrict__ bb2,
    const float* __restrict__ ow, const float* __restrict__ ob,
    float* __restrict__ out) {
  __shared__ float lsS[DW], lsH[DW];
  int t = threadIdx.x;
  for (int c = t; c < DW; c += 256) {
    float m = gB[c] * (1.f / BATCH);
    float var = gB2[c] * (1.f / BATCH) - m * m;
    float sc = g2[c] * rsqrtf(var + BN_EPS);
    lsS[c] = sc;
    lsH[c] = bb2[c] - m * sc;
  }
  __syncthreads();
  int lane = t & 63, w = t >> 6;
  int b = blockIdx.x * 4 + w;
  float acc = 0.f;
  for (int j = lane; j < 593; j += 64) {
    float v;
    if (j == 0)       v = lp[b];
    else if (j < 193) v = res[(size_t)b * 192 + (j - 1)];
    else {
      int c = j - 193;
      v = fmaxf(fmaf(y2[(size_t)b * DW + c], lsS[c], lsH[c]), 0.f);
    }
    acc = fmaf(v, ow[j], acc);
  }
#pragma unroll
  for (int k = 1; k < 64; k <<= 1) acc += __shfl_xor(acc, k);
  if (lane == 0) out[b] = acc + ob[0];
}

// ---------------------------------------------------------------------------
extern "C" void kernel_launch(void* const* d_in, const int* in_sizes, int n_in,
                              void* d_out, int out_size, void* d_ws, size_t ws_size,
                              hipStream_t stream) {
  const int*   feat_index = (const int*)d_in[0];
  const float* emb = (const float*)d_in[2];
  const float* lw  = (const float*)d_in[3];
  const float* lb  = (const float*)d_in[4];
  const float* w1  = (const float*)d_in[5];
  const float* b1  = (const float*)d_in[6];
  const float* w2  = (const float*)d_in[7];
  const float* b2  = (const float*)d_in[8];
  const float* dw1 = (const float*)d_in[9];
  const float* db1 = (const float*)d_in[10];
  const float* g1  = (const float*)d_in[11];
  const float* bb1 = (const float*)d_in[12];
  const float* dw2 = (const float*)d_in[13];
  const float* db2 = (const float*)d_in[14];
  const float* g2  = (const float*)d_in[15];
  const float* bb2 = (const float*)d_in[16];
  const float* ow  = (const float*)d_in[17];
  const float* ob  = (const float*)d_in[18];

  float* ws   = (float*)d_ws;
  u16*  flatb = (u16*)ws;                  // 4096*640 bf16
  float* y1   = ws + 1310720;              // 4096*400 f32
  float* res  = ws + 2949120;              // 4096*192 f32
  float* lp   = ws + 3735552;              // 4096
  float* gA   = ws + 3741248;              // 400 sum
  float* gA2  = gA + 400;
  float* gB   = gA2 + 400;
  float* gB2  = gB + 400;                  // gstat block: 1600 contiguous
  u16*  nxtg  = (u16*)(ws + 3742848);      // 4096*16*64 bf16
  float* y2   = ws + 3742848;              // alias nxtg (dead after cin2)
  u16*  wp1   = (u16*)(ws + 5840000);
  u16*  wp2   = (u16*)(ws + 5999744);
  u16*  wpd1  = (u16*)(ws + 6159488);
  u16*  wpd2  = (u16*)(ws + 6287488);      // ends 6,370,688 f (25.5 MB)
  float* out  = (float*)d_out;

  k_gp<<<BATCH + PREP_B, 256, 0, stream>>>(feat_index, emb, lw, lb, w1, w2,
      dw1, dw2, flatb, lp, wp1, wp2, wpd1, wpd2, gA);
  k_cin_mfma<false><<<dim3(BATCH / 8, 2), 256, 0, stream>>>(
      flatb, nullptr, wp1, b1, nxtg, res);
  k_cin_mfma<true><<<dim3(BATCH / 8, 2), 256, 0, stream>>>(
      flatb, nxtg, wp2, b2, nullptr, res);
  k_gemm_mfma<false, NKS1, IN_DIM, AK1><<<dim3(BATCH / 64, 25), 256, 0, stream>>>(
      flatb, nullptr, wpd1, db1, nullptr, nullptr, nullptr, nullptr, y1, gA, gA2);
  k_gemm_mfma<true, NKS2, DW, 0><<<dim3(BATCH / 64, 25), 256, 0, stream>>>(
      nullptr, y1, wpd2, db2, gA, gA2, g1, bb1, y2, gB, gB2);
  k_final<<<BATCH / 4, 256, 0, stream>>>(lp, res, y2, gB, gB2, g2, bb2, ow, ob, out);
}

// Round 6
// 281.220 us; speedup vs baseline: 2.3365x; 2.3365x over previous
//
#include <hip/hip_runtime.h>

// Problem constants
#define BATCH   4096
#define NF      39          // num_field
#define ED      16          // embedding size
#define IN_DIM  624         // NF*ED
#define DW      400
#define BN_EPS  1e-5f
#define KTOT    2496        // CIN K = 39 m * 64 h (h padded)
#define NKSG    78          // KTOT/32
#define AK1     640         // padded deep K for layer 1 input (624 -> 640)
#define NKS1    20          // AK1/32
#define NKS2    13          // 400 -> 416 padded

typedef __attribute__((ext_vector_type(8))) short short8;
typedef __attribute__((ext_vector_type(4))) float f32x4;
typedef unsigned short u16;

__device__ inline unsigned pack2_trunc(float a, float b) {
  return (__float_as_uint(a) >> 16) | (__float_as_uint(b) & 0xffff0000u);
}
__device__ inline unsigned bf16_rne(float f) {
  unsigned u = __float_as_uint(f);
  u += 0x7fff + ((u >> 16) & 1);
  return u >> 16;
}
__device__ inline float bf2f(u16 v) { return __uint_as_float((unsigned)v << 16); }

#define CIN_E (NKSG * 128 * 32)
#define D1_E  (NKS1 * 400 * 32)
#define D2_E  (NKS2 * 400 * 32)
#define PREP_E (CIN_E + D1_E + D2_E + 1600)
#define PREP_B ((PREP_E + 255) / 256)

// ---------------------------------------------------------------------------
// Merged kernel: blocks < BATCH do the embedding gather (+linear part);
// blocks >= BATCH do weight pre-pack + BN-stat zeroing. One launch.
// ---------------------------------------------------------------------------
__global__ __launch_bounds__(256) void k_gp(const int* __restrict__ idx,
    const float* __restrict__ emb, const float* __restrict__ lw,
    const float* __restrict__ lb, const float* __restrict__ w1,
    const float* __restrict__ w2, const float* __restrict__ dw1,
    const float* __restrict__ dw2, u16* __restrict__ flatb,
    float* __restrict__ lp, u16* __restrict__ wp1, u16* __restrict__ wp2,
    u16* __restrict__ wpd1, u16* __restrict__ wpd2, float* __restrict__ gstat) {
  int t = threadIdx.x;
  if (blockIdx.x < BATCH) {
    int b = blockIdx.x;
    __shared__ int si[NF];
    __shared__ float r4[4];
    if (t < NF) si[t] = idx[b * NF + t];
    __syncthreads();
    float acc = 0.f;
#pragma unroll
    for (int i = 0; i < 3; i++) {
      int e = t + i * 256;
      if (e < IN_DIM) {
        float v = emb[(size_t)si[e >> 4] * ED + (e & 15)];
        flatb[(size_t)b * AK1 + e] = (u16)bf16_rne(v);
        acc = fmaf(v, lw[e], acc);
      } else if (e < AK1) {
        flatb[(size_t)b * AK1 + e] = 0;
      }
    }
#pragma unroll
    for (int k = 1; k < 64; k <<= 1) acc += __shfl_xor(acc, k);
    if ((t & 63) == 0) r4[t >> 6] = acc;
    __syncthreads();
    if (t == 0) lp[b] = r4[0] + r4[1] + r4[2] + r4[3] + lb[0];
  } else {
    int e = (blockIdx.x - BATCH) * 256 + t;
    if (e < CIN_E) {
      int ksg = e >> 12, r = e & 4095, n = r >> 5, kk = r & 31;
      int k = ksg * 32 + kk, h = k & 63, m = k >> 6;
      float v1 = (h < NF) ? w1[(size_t)n * (NF * NF) + h * NF + m] : 0.f;
      float v2 = w2[(size_t)n * (64 * NF) + h * NF + m];
      wp1[e] = (u16)bf16_rne(v1);
      wp2[e] = (u16)bf16_rne(v2);
    } else if (e < CIN_E + D1_E) {
      int e2 = e - CIN_E;
      int ksg = e2 / 12800, r = e2 - ksg * 12800, col = r >> 5, kk = r & 31;
      int k = ksg * 32 + kk;
      wpd1[e2] = (k < IN_DIM) ? (u16)bf16_rne(dw1[(size_t)k * DW + col]) : 0;
    } else if (e < CIN_E + D1_E + D2_E) {
      int e2 = e - CIN_E - D1_E;
      int ksg = e2 / 12800, r = e2 - ksg * 12800, col = r >> 5, kk = r & 31;
      int k = ksg * 32 + kk;
      wpd2[e2] = (k < DW) ? (u16)bf16_rne(dw2[(size_t)k * DW + col]) : 0;
    } else if (e < PREP_E) {
      gstat[e - CIN_E - D1_E - D2_E] = 0.f;
    }
  }
}

// ---------------------------------------------------------------------------
// CIN via MFMA (r4 structure, no reg cap beyond (256,2) -> no spill).
// Grid (BATCH/16, 2): blockIdx.y picks o-half (64 cols = 4 n-tiles).
// Wave = 4 samples x 4 n-tiles; B-frags double-buffered in registers;
// xv prefetched one m ahead. No LDS, no barriers.
// Wave phase stagger: odd waves traverse m circularly starting at m=20 so
// the two resident waves/SIMD anti-correlate VALU-repack vs MFMA phases.
// ---------------------------------------------------------------------------
template <bool LAY2>
__global__ __launch_bounds__(256, 2) void k_cin_mfma(
    const u16* __restrict__ flatb, const u16* __restrict__ nxtg,
    const u16* __restrict__ wp, const float* __restrict__ bias,
    u16* __restrict__ nxt_out, float* __restrict__ res) {
  int t = threadIdx.x;
  int w = t >> 6, lane = t & 63;
  int nl = lane & 15, q = lane >> 4;
  int d = nl;
  int b0 = blockIdx.x * 16 + w * 4;
  int c0 = blockIdx.y * 64;            // o-half base
  int m0 = (w & 1) * 20;               // phase stagger

  // s1 registers: nxr[si][ks][w4] = packed bf16 pair, h = ks*32+q*8+2*w4(+1)
  unsigned nxr[4][2][4];
  if (LAY2) {
#pragma unroll
    for (int si = 0; si < 4; si++)
#pragma unroll
      for (int ks = 0; ks < 2; ks++) {
        uint4 v = *(const uint4*)(nxtg +
            (((size_t)(b0 + si) * 16 + d) * 64 + ks * 32 + q * 8));
        nxr[si][ks][0] = v.x; nxr[si][ks][1] = v.y;
        nxr[si][ks][2] = v.z; nxr[si][ks][3] = v.w;
      }
  } else {
#pragma unroll
    for (int si = 0; si < 4; si++)
#pragma unroll
      for (int ks = 0; ks < 2; ks++)
#pragma unroll
        for (int w4 = 0; w4 < 4; w4++) {
          int h0 = ks * 32 + q * 8 + 2 * w4;
          int h1 = h0 + 1;
          unsigned u0 = (h0 < NF) ? flatb[(size_t)(b0 + si) * AK1 + h0 * 16 + d] : 0;
          unsigned u1 = (h1 < NF) ? flatb[(size_t)(b0 + si) * AK1 + h1 * 16 + d] : 0;
          nxr[si][ks][w4] = u0 | (u1 << 16);
        }
  }

  f32x4 acc[4][4];
#pragma unroll
  for (int si = 0; si < 4; si++)
#pragma unroll
    for (int nt = 0; nt < 4; nt++) acc[si][nt] = (f32x4){0.f, 0.f, 0.f, 0.f};

  const u16* wbase = wp + (size_t)(c0 + nl) * 32 + q * 8;
  short8 bfr[2][4];
#pragma unroll
  for (int nt = 0; nt < 4; nt++)
    bfr[0][nt] = *(const short8*)(wbase + (size_t)(m0 * 2) * 4096 + nt * 512);

  float xv[4], xvn[4];
#pragma unroll
  for (int si = 0; si < 4; si++)
    xv[si] = bf2f(flatb[(size_t)(b0 + si) * AK1 + m0 * 16 + d]);

  int m = m0;
  for (int i = 0; i < NF; i++) {
    int mi = m0 + i + 1;
    int mn = mi - ((mi >= NF) ? NF : 0);   // next m (circular)
    if (i + 1 < NF) {
#pragma unroll
      for (int si = 0; si < 4; si++)
        xvn[si] = bf2f(flatb[(size_t)(b0 + si) * AK1 + mn * 16 + d]);
    }
#pragma unroll
    for (int ks = 0; ks < 2; ks++) {
      int nx = ks ^ 1;
      // prefetch next ksg's B-fragments (buffer parity == ks parity)
      int nksg = (ks == 0) ? (m * 2 + 1) : ((i + 1 < NF) ? mn * 2 : -1);
      if (nksg >= 0) {
        const u16* wb = wbase + (size_t)nksg * 4096;
#pragma unroll
        for (int nt = 0; nt < 4; nt++)
          bfr[nx][nt] = *(const short8*)(wb + nt * 512);
      }
      short8 afr[4];
#pragma unroll
      for (int si = 0; si < 4; si++) {
        union { unsigned u[4]; short8 s; } a;
#pragma unroll
        for (int w4 = 0; w4 < 4; w4++) {
          unsigned u = nxr[si][ks][w4];
          float lo = __uint_as_float(u << 16) * xv[si];
          float hi = __uint_as_float(u & 0xffff0000u) * xv[si];
          a.u[w4] = pack2_trunc(lo, hi);
        }
        afr[si] = a.s;
      }
#pragma unroll
      for (int nt = 0; nt < 4; nt++)
#pragma unroll
        for (int si = 0; si < 4; si++)
          acc[si][nt] = __builtin_amdgcn_mfma_f32_16x16x32_bf16(
              afr[si], bfr[ks][nt], acc[si][nt], 0, 0, 0);
    }
#pragma unroll
    for (int si = 0; si < 4; si++) xv[si] = xvn[si];
    m = mn;
  }

  // Epilogue. C layout: col = nl (within n-tile), row d' = q*4 + r.
#pragma unroll
  for (int si = 0; si < 4; si++) {
    int b = b0 + si;
#pragma unroll
    for (int nt = 0; nt < 4; nt++) {
      int o = c0 + nt * 16 + nl;
      float bi = bias[o];
      if (!LAY2 && c0 == 0) {
#pragma unroll
        for (int r = 0; r < 4; r++) {
          float v = fmaxf(acc[si][nt][r] + bi, 0.f);
          nxt_out[((size_t)b * 16 + q * 4 + r) * 64 + o] = (u16)bf16_rne(v);
        }
      } else {
        float s = 0.f;
#pragma unroll
        for (int r = 0; r < 4; r++) s += fmaxf(acc[si][nt][r] + bi, 0.f);
        s += __shfl_xor(s, 16);
        s += __shfl_xor(s, 32);
        if (q == 0) {
          int ri = LAY2 ? (64 + o) : (o - 64);
          res[(size_t)b * 192 + ri] = s;
        }
      }
    }
  }
}

// ---------------------------------------------------------------------------
// Deep-tower GEMM via MFMA, occupancy-first: grid (M/64, 25), wave = 16 rows
// x 16 cols (1 n-tile), A+B double-buffered. BN_A folds the *previous*
// layer's BN finalize in-block (from gsIn/gs2In) and applies BN+ReLU to A.
// Fused BN stats of C -> global atomics (gs/gs2).
// ---------------------------------------------------------------------------
template <bool BN_A, int NKS, int KREAL, int AK>
__global__ __launch_bounds__(256) void k_gemm_mfma(
    const u16* __restrict__ Abf, const float* __restrict__ Af32,
    const u16* __restrict__ wp, const float* __restrict__ bias,
    const float* __restrict__ gsIn, const float* __restrict__ gs2In,
    const float* __restrict__ bng, const float* __restrict__ bnb,
    float* __restrict__ C, float* __restrict__ gs, float* __restrict__ gs2) {
  __shared__ float lsS[NKS * 32], lsH[NKS * 32];
  __shared__ float lred[32];
  int t = threadIdx.x;
  if (BN_A) {
    for (int c = t; c < NKS * 32; c += 256) {
      float sc = 0.f, sh = 0.f;
      if (c < DW) {
        float m = gsIn[c] * (1.f / BATCH);
        float var = gs2In[c] * (1.f / BATCH) - m * m;
        sc = bng[c] * rsqrtf(var + BN_EPS);
        sh = bnb[c] - m * sc;
      }
      lsS[c] = sc; lsH[c] = sh;
    }
  }
  if (t < 32) lred[t] = 0.f;
  __syncthreads();

  int w = t >> 6, lane = t & 63;
  int nl = lane & 15, q = lane >> 4;
  int row = blockIdx.x * 64 + w * 16 + nl;
  int c0 = blockIdx.y * 16;
  f32x4 acc = (f32x4){0.f, 0.f, 0.f, 0.f};

  short8 araw[2]; f32x4 fraw0[2], fraw1[2]; short8 braw[2];
  auto loadA_raw = [&](int ksg, int buf) {
    int kb = ksg * 32 + q * 8;
    if (!BN_A) {
      araw[buf] = *(const short8*)(Abf + (size_t)row * AK + kb);
    } else {
      if (kb + 8 <= KREAL) {
        fraw0[buf] = *(const f32x4*)(Af32 + (size_t)row * KREAL + kb);
        fraw1[buf] = *(const f32x4*)(Af32 + (size_t)row * KREAL + kb + 4);
      } else {
        fraw0[buf] = (f32x4){0.f,0.f,0.f,0.f};
        fraw1[buf] = (f32x4){0.f,0.f,0.f,0.f};
      }
    }
    braw[buf] = *(const short8*)(wp + (size_t)ksg * (400 * 32) +
                                 (size_t)(c0 + nl) * 32 + q * 8);
  };
  auto cookA = [&](int ksg, int buf) -> short8 {
    if (!BN_A) return araw[buf];
    int kb = ksg * 32 + q * 8;
    f32x4 s0 = *(const f32x4*)&lsS[kb], h0 = *(const f32x4*)&lsH[kb];
    f32x4 s1 = *(const f32x4*)&lsS[kb + 4], h1 = *(const f32x4*)&lsH[kb + 4];
    union { unsigned u[4]; short8 s; } a;
    float v0 = fmaxf(fmaf(fraw0[buf][0], s0[0], h0[0]), 0.f);
    float v1 = fmaxf(fmaf(fraw0[buf][1], s0[1], h0[1]), 0.f);
    float v2 = fmaxf(fmaf(fraw0[buf][2], s0[2], h0[2]), 0.f);
    float v3 = fmaxf(fmaf(fraw0[buf][3], s0[3], h0[3]), 0.f);
    float v4 = fmaxf(fmaf(fraw1[buf][0], s1[0], h1[0]), 0.f);
    float v5 = fmaxf(fmaf(fraw1[buf][1], s1[1], h1[1]), 0.f);
    float v6 = fmaxf(fmaf(fraw1[buf][2], s1[2], h1[2]), 0.f);
    float v7 = fmaxf(fmaf(fraw1[buf][3], s1[3], h1[3]), 0.f);
    a.u[0] = bf16_rne(v0) | (bf16_rne(v1) << 16);
    a.u[1] = bf16_rne(v2) | (bf16_rne(v3) << 16);
    a.u[2] = bf16_rne(v4) | (bf16_rne(v5) << 16);
    a.u[3] = bf16_rne(v6) | (bf16_rne(v7) << 16);
    return a.s;
  };

  loadA_raw(0, 0);
#pragma unroll 4
  for (int ksg = 0; ksg < NKS; ksg++) {
    int cur = ksg & 1;
    if (ksg + 1 < NKS) loadA_raw(ksg + 1, cur ^ 1);
    short8 afr = cookA(ksg, cur);
    acc = __builtin_amdgcn_mfma_f32_16x16x32_bf16(afr, braw[cur], acc, 0, 0, 0);
  }

  int rbase = blockIdx.x * 64 + w * 16 + q * 4;
  int col = c0 + nl;
  float bi = bias[col];
  float s = 0.f, s2 = 0.f;
#pragma unroll
  for (int r = 0; r < 4; r++) {
    float v = acc[r] + bi;
    C[(size_t)(rbase + r) * DW + col] = v;
    s += v; s2 = fmaf(v, v, s2);
  }
  s += __shfl_xor(s, 16); s2 += __shfl_xor(s2, 16);
  s += __shfl_xor(s, 32); s2 += __shfl_xor(s2, 32);
  if (q == 0) {
    atomicAdd(&lred[nl], s);
    atomicAdd(&lred[16 + nl], s2);
  }
  __syncthreads();
  if (t < 16)       atomicAdd(&gs[c0 + t], lred[t]);
  else if (t < 32)  atomicAdd(&gs2[c0 + t - 16], lred[t]);
}

// ---------------------------------------------------------------------------
// Final concat + dot, with BN2 finalize folded in-block.
// ---------------------------------------------------------------------------
__global__ __launch_bounds__(256) void k_final(const float* __restrict__ lp,
    const float* __restrict__ res, const float* __restrict__ y2,
    const float* __restrict__ gB, const float* __restrict__ gB2,
    const float* __restrict__ g2, const float* __restrict__ bb2,
    const float* __restrict__ ow, const float* __restrict__ ob,
    float* __restrict__ out) {
  __shared__ float lsS[DW], lsH[DW];
  int t = threadIdx.x;
  for (int c = t; c < DW; c += 256) {
    float m = gB[c] * (1.f / BATCH);
    float var = gB2[c] * (1.f / BATCH) - m * m;
    float sc = g2[c] * rsqrtf(var + BN_EPS);
    lsS[c] = sc;
    lsH[c] = bb2[c] - m * sc;
  }
  __syncthreads();
  int lane = t & 63, w = t >> 6;
  int b = blockIdx.x * 4 + w;
  float acc = 0.f;
  for (int j = lane; j < 593; j += 64) {
    float v;
    if (j == 0)       v = lp[b];
    else if (j < 193) v = res[(size_t)b * 192 + (j - 1)];
    else {
      int c = j - 193;
      v = fmaxf(fmaf(y2[(size_t)b * DW + c], lsS[c], lsH[c]), 0.f);
    }
    acc = fmaf(v, ow[j], acc);
  }
#pragma unroll
  for (int k = 1; k < 64; k <<= 1) acc += __shfl_xor(acc, k);
  if (lane == 0) out[b] = acc + ob[0];
}

// ---------------------------------------------------------------------------
extern "C" void kernel_launch(void* const* d_in, const int* in_sizes, int n_in,
                              void* d_out, int out_size, void* d_ws, size_t ws_size,
                              hipStream_t stream) {
  const int*   feat_index = (const int*)d_in[0];
  const float* emb = (const float*)d_in[2];
  const float* lw  = (const float*)d_in[3];
  const float* lb  = (const float*)d_in[4];
  const float* w1  = (const float*)d_in[5];
  const float* b1  = (const float*)d_in[6];
  const float* w2  = (const float*)d_in[7];
  const float* b2  = (const float*)d_in[8];
  const float* dw1 = (const float*)d_in[9];
  const float* db1 = (const float*)d_in[10];
  const float* g1  = (const float*)d_in[11];
  const float* bb1 = (const float*)d_in[12];
  const float* dw2 = (const float*)d_in[13];
  const float* db2 = (const float*)d_in[14];
  const float* g2  = (const float*)d_in[15];
  const float* bb2 = (const float*)d_in[16];
  const float* ow  = (const float*)d_in[17];
  const float* ob  = (const float*)d_in[18];

  float* ws   = (float*)d_ws;
  u16*  flatb = (u16*)ws;                  // 4096*640 bf16
  float* y1   = ws + 1310720;              // 4096*400 f32
  float* res  = ws + 2949120;              // 4096*192 f32
  float* lp   = ws + 3735552;              // 4096
  float* gA   = ws + 3741248;              // 400 sum
  float* gA2  = gA + 400;
  float* gB   = gA2 + 400;
  float* gB2  = gB + 400;                  // gstat block: 1600 contiguous
  u16*  nxtg  = (u16*)(ws + 3742848);      // 4096*16*64 bf16
  float* y2   = ws + 3742848;              // alias nxtg (dead after cin2)
  u16*  wp1   = (u16*)(ws + 5840000);
  u16*  wp2   = (u16*)(ws + 5999744);
  u16*  wpd1  = (u16*)(ws + 6159488);
  u16*  wpd2  = (u16*)(ws + 6287488);      // ends 6,370,688 f (25.5 MB)
  float* out  = (float*)d_out;

  k_gp<<<BATCH + PREP_B, 256, 0, stream>>>(feat_index, emb, lw, lb, w1, w2,
      dw1, dw2, flatb, lp, wp1, wp2, wpd1, wpd2, gA);
  k_cin_mfma<false><<<dim3(BATCH / 16, 2), 256, 0, stream>>>(
      flatb, nullptr, wp1, b1, nxtg, res);
  k_cin_mfma<true><<<dim3(BATCH / 16, 2), 256, 0, stream>>>(
      flatb, nxtg, wp2, b2, nullptr, res);
  k_gemm_mfma<false, NKS1, IN_DIM, AK1><<<dim3(BATCH / 64, 25), 256, 0, stream>>>(
      flatb, nullptr, wpd1, db1, nullptr, nullptr, nullptr, nullptr, y1, gA, gA2);
  k_gemm_mfma<true, NKS2, DW, 0><<<dim3(BATCH / 64, 25), 256, 0, stream>>>(
      nullptr, y1, wpd2, db2, gA, gA2, g1, bb1, y2, gB, gB2);
  k_final<<<BATCH / 4, 256, 0, stream>>>(lp, res, y2, gB, gB2, g2, bb2, ow, ob, out);
}